// Round 15
// baseline (75.782 us; speedup 1.0000x reference)
//
#include <hip/hip_runtime.h>
#include <hip/hip_bf16.h>
#include <hip/hip_fp16.h>

typedef short bf16x8 __attribute__((ext_vector_type(8)));
typedef _Float16 h8 __attribute__((ext_vector_type(8)));
typedef _Float16 h2v __attribute__((ext_vector_type(2)));
typedef __fp16 fp16x2 __attribute__((ext_vector_type(2)));   // cvt_pkrtz return type
typedef float f32x16 __attribute__((ext_vector_type(16)));
typedef unsigned int uint32;

#define S 2048
#define D 64
#define NBH 24

#define GLOAD16(g, l) __builtin_amdgcn_global_load_lds(                      \
    (const __attribute__((address_space(1))) unsigned int*)(g),              \
    (__attribute__((address_space(3))) unsigned int*)(l), 16, 0, 0)

__device__ __forceinline__ int cvtpk_bf16(float lo, float hi) {
    int r;
    asm("v_cvt_pk_bf16_f32 %0, %1, %2" : "=v"(r) : "v"(lo), "v"(hi));
    return r;
}

// Fused prep (float4-vectorized): L2-normalize Q,K rows (fp32->bf16) + transpose V
// (fp16, key-mask folded in).
__global__ __launch_bounds__(256) void prep(const float* __restrict__ Q,
                                            const float* __restrict__ K,
                                            const float* __restrict__ V,
                                            const int* __restrict__ mask,
                                            __hip_bfloat16* __restrict__ Qn,
                                            __hip_bfloat16* __restrict__ Kn,
                                            __half* __restrict__ Vt) {
    __shared__ float tile[64][65];
    const int NBQK = 2 * NBH * S / 16;            // 6144 norm blocks
    int blk = blockIdx.x;
    int t = threadIdx.x;
    if (blk < NBQK) {
        int l16 = t & 15;
        int row = blk * 16 + (t >> 4);
        int half = row >= NBH * S;
        const float* in = half ? K : Q;
        __hip_bfloat16* out = half ? Kn : Qn;
        row -= half * NBH * S;
        float4 x = *(const float4*)(in + (size_t)row * 64 + l16 * 4);
        float ss = x.x * x.x + x.y * x.y + x.z * x.z + x.w * x.w;
        #pragma unroll
        for (int m = 1; m <= 8; m <<= 1) ss += __shfl_xor(ss, m, 64);
        float sc = rsqrtf(ss + 1e-6f);
        int2 pk = { cvtpk_bf16(x.x * sc, x.y * sc), cvtpk_bf16(x.z * sc, x.w * sc) };
        *(int2*)(out + (size_t)row * 64 + l16 * 4) = pk;
        return;
    }
    blk -= NBQK;                                  // 768 transpose blocks
    int bh = blk >> 5;
    int b  = bh / 12;
    int s0 = (blk & 31) << 6;
    #pragma unroll
    for (int i = 0; i < 16; ++i) {
        int idx = i * 256 + t;
        int sl = idx >> 6, d = idx & 63;
        float mv = (float)mask[b * S + s0 + sl];
        tile[sl][d] = V[(size_t)bh * S * D + (size_t)(s0 + sl) * D + d] * mv;
    }
    __syncthreads();
    #pragma unroll
    for (int i = 0; i < 16; ++i) {
        int idx = i * 256 + t;
        int d = idx >> 6, sl = idx & 63;
        Vt[(size_t)bh * S * D + (size_t)d * S + s0 + sl] = __float2half(tile[sl][d]);
    }
}

// Main: 512-thread blocks (8 waves), block = (bh, 256 q-rows, key-range S/SPLITS).
// Grid = 24 x 8 x SPLITS; at SPLITS=4 -> 768 blocks = 3/CU.
// __launch_bounds__(512, 6): force reg budget <= 85/wave so 3 blocks fit per CU
// (R14 post-mortem: ~100 unified VGPR+AGPR capped residency at 2 blocks/CU ->
// [2,1] dispatch batches = the ~53us floor).
// Register diet: NO precomputed LDS-offset arrays -- all ds_read addresses derive
// from A (swizzle nibble) and rowb (c31*128) + compile-time XOR imms + ds imm
// offset. LDS slot(row,u) = u ^ (row&7) ^ (row>>3) ^ ((u&1)<<2); stage applies
// the inverse on the global source address (G21).
// Schedule (R7 post-mortem, SOUND): vmcnt(0) -> s_barrier -> STAGE(next) ->
// COMPUTE(cur). NEVER wait vmcnt after the barrier (vmcnt is per-wave).
template<int SPLITS>
__global__ __launch_bounds__(512, 6) void yoso_main(const __hip_bfloat16* __restrict__ Qn,
                                                    const __hip_bfloat16* __restrict__ Kn,
                                                    const __half* __restrict__ Vt,
                                                    const int* __restrict__ mask,
                                                    const int* __restrict__ hlen_ptr,
                                                    void* __restrict__ outp) {
    __shared__ char lds[2][16384];   // per buf: [0,8192)=K tile, [8192,16384)=V tile

    const int QT = 8;                             // 256-q tiles
    const int blk = blockIdx.x;
    const int bh  = blk / (QT * SPLITS);
    const int rr  = blk % (QT * SPLITS);
    const int q0  = (rr / SPLITS) << 8;
    const int kq  = rr % SPLITS;
    const int kbase = kq * (S / SPLITS);
    const int NTt   = S / SPLITS / 64;

    const int b    = bh / 12;
    const int t    = threadIdx.x;
    const int w    = t >> 6;                      // 0..7
    const int lane = t & 63;
    const int h    = lane >> 5;
    const int c31  = lane & 31;
    const int hcode = hlen_ptr[0];
    const size_t head = (size_t)bh * S * D;

    // ---- staging source offsets (inverse swizzle on global address) ----
    const int s_  = lane & 7;
    const int r3l = lane >> 3;
    const int e1  = s_ ^ r3l ^ (w & 7);
    const int u1  = e1 ^ ((e1 & 1) << 2);
    const int kgo1 = (8 * w + r3l) * 128 + u1 * 16;
    const int vgo1 = (8 * w + r3l) * 4096 + u1 * 16;
    const char* Kg = (const char*)(Kn + head);   // key-row stride 128 B
    const char* Vg = (const char*)(Vt + head);   // d-row stride 4096 B

    // ---- compact LDS-read address state (2 live regs) ----
    char* ldsc = &lds[0][0];
    const int A    = (c31 & 7) ^ (c31 >> 3) ^ (h << 2) ^ h;   // swizzle nibble, 0..7
    const int rowb = c31 * 128;                               // row base bytes

    // Q B-fragments: wave w owns q rows q0 + w*32 + c31 (prep-normalized bf16)
    bf16x8 qf[4];
    {
        const __hip_bfloat16* qp = Qn + head + (size_t)(q0 + w * 32 + c31) * D + h * 8;
        qf[0] = *(const bf16x8*)(qp);
        qf[1] = *(const bf16x8*)(qp + 16);
        qf[2] = *(const bf16x8*)(qp + 32);
        qf[3] = *(const bf16x8*)(qp + 48);
    }
    asm volatile("" :: "v"(qf[0]), "v"(qf[1]), "v"(qf[2]), "v"(qf[3]));

    const f32x16 z16 = {0,0,0,0,0,0,0,0,0,0,0,0,0,0,0,0};
    f32x16 xacc0 = z16, xacc1 = z16;

    const bool  p9 = (hcode == 9);
    const float hf = (float)hcode;

    // packed fp16 constants (native vector ops -> v_pk_*_f16)
    const h2v one2  = {(_Float16)1.0f,  (_Float16)1.0f};
    const h2v half2 = {(_Float16)0.5f,  (_Float16)0.5f};
    const h2v zero2 = {(_Float16)0.0f,  (_Float16)0.0f};
    const h2v q3c = {(_Float16)-0.00596128f, (_Float16)-0.00596128f};
    const h2v q2c = {(_Float16)-0.00575336f, (_Float16)-0.00575336f};
    const h2v q1c = {(_Float16)-0.03812704f, (_Float16)-0.03812704f};
    const h2v q0c = {(_Float16)-0.4501324f,  (_Float16)-0.4501324f};

    auto STAGE = [&](int base, int k0) {
        const char* kb = Kg + (size_t)k0 * 128;
        const char* vb = Vg + (size_t)k0 * 2;
        char* Kl = ldsc + base;
        char* Vl = Kl + 8192;
        GLOAD16(kb + kgo1, Kl + w * 1024);        // 512 thr x 16B = full 8KB K tile
        GLOAD16(vb + vgo1, Vl + w * 1024);        // full 8KB V tile
    };

    // generic-hcode scalar fallback
    auto XFgen = [&](float s) -> float {
        float z  = fmaxf(1.0f - fabsf(s), 0.0f);
        float qp = ((0.00596128f * z + 0.00575336f) * z + 0.03812704f) * z + 0.4501324f;
        float tp = 0.5f - __builtin_amdgcn_sqrtf(z) * qp;
        float x  = 0.5f + __builtin_copysignf(tp, s);
        return __builtin_amdgcn_exp2f(hf * __builtin_amdgcn_logf(x));
    };

    auto COMPUTE = [&](int bufbase) {
        #pragma unroll
        for (int kh2 = 0; kh2 < 2; ++kh2) {
            // K-frag addr: slot = A ^ (2kd) ^ (kh2<<2); byte = rowb + slot*16,
            // imm = bufbase + kh2*4096 (K region). All imms compile-time.
            __builtin_amdgcn_s_setprio(1);
            f32x16 sacc;
            {
                const char* p0 = ldsc + bufbase + kh2 * 4096 + rowb
                               + ((A ^ (0 ^ (kh2 << 2))) << 4);
                sacc = __builtin_amdgcn_mfma_f32_32x32x16_bf16(
                    *(const bf16x8*)(p0), qf[0], z16, 0, 0, 0);
            }
            #pragma unroll
            for (int kd = 1; kd < 4; ++kd) {
                const char* pk = ldsc + bufbase + kh2 * 4096 + rowb
                               + ((A ^ ((2 * kd) ^ (kh2 << 2))) << 4);
                sacc = __builtin_amdgcn_mfma_f32_32x32x16_bf16(
                    *(const bf16x8*)(pk), qf[kd], sacc, 0, 0, 0);
            }
            __builtin_amdgcn_s_setprio(0);

            // w = x^h, x = 0.5 + copysign(0.5 - sqrt(z)*q(z), s), z = 1-|s|
            // packed fp16: 2 elems per op, sign bits ride along in the pack.
            int u_[8];
            union HU { h2v v; fp16x2 p; uint32 u; };
            if (p9) {
                #pragma unroll
                for (int i = 0; i < 8; ++i) {
                    HU cv; cv.p = __builtin_amdgcn_cvt_pkrtz(sacc[2 * i], sacc[2 * i + 1]);
                    uint32 spb = cv.u;
                    HU za; za.u = spb & 0x7FFF7FFFu;                 // |s|
                    h2v z = one2 - za.v;
                    z = __builtin_elementwise_max(z, zero2);          // max(1-|s|,0)
                    h2v rt = __builtin_elementwise_sqrt(z);
                    h2v q = q3c * z + q2c;                            // -q(z) Horner
                    q = q * z + q1c;
                    q = q * z + q0c;
                    HU tb; tb.v = q * rt + half2;                     // 0.5 - q(z)*sqrt(z) >= 0
                    HU xb; xb.u = (tb.u & 0x7FFF7FFFu) | (spb & 0x80008000u);
                    h2v x = xb.v + half2;                             // 0.5 + copysign(tp, s)
                    h2v x2 = x * x;
                    h2v x4 = x2 * x2;
                    h2v x8 = x4 * x4;
                    HU wr; wr.v = x8 * x;                             // x^9, packed fp16
                    u_[i] = (int)wr.u;
                }
            } else {
                #pragma unroll
                for (int i = 0; i < 8; ++i) {
                    HU cv;
                    cv.p = __builtin_amdgcn_cvt_pkrtz(XFgen(sacc[2 * i]),
                                                      XFgen(sacc[2 * i + 1]));
                    u_[i] = (int)cv.u;
                }
            }
            asm("v_permlane32_swap_b32 %0, %1" : "+v"(u_[0]), "+v"(u_[2]));
            asm("v_permlane32_swap_b32 %0, %1" : "+v"(u_[1]), "+v"(u_[3]));
            asm("v_permlane32_swap_b32 %0, %1" : "+v"(u_[4]), "+v"(u_[6]));
            asm("v_permlane32_swap_b32 %0, %1" : "+v"(u_[5]), "+v"(u_[7]));
            union { int i[4]; h8 v; } f0, f1;
            f0.i[0] = u_[0]; f0.i[1] = u_[1]; f0.i[2] = u_[2]; f0.i[3] = u_[3];
            f1.i[0] = u_[4]; f1.i[1] = u_[5]; f1.i[2] = u_[6]; f1.i[3] = u_[7];

            // V-frag addr: slot = A ^ (kb2<<1) ^ (kh2<<2) [^4 for d-hi rows],
            // byte = rowb + slot*16, imm = bufbase + 8192 [+4096 for d-hi].
            h8 vf00, vf01, vf10, vf11;
            {
                const int vx = (kh2 << 2);
                vf00 = *(const h8*)(ldsc + bufbase + 8192 + rowb
                                    + ((A ^ (0 ^ vx)) << 4));
                vf01 = *(const h8*)(ldsc + bufbase + 8192 + 4096 + rowb
                                    + ((A ^ (0 ^ vx) ^ 4) << 4));
                vf10 = *(const h8*)(ldsc + bufbase + 8192 + rowb
                                    + ((A ^ (2 ^ vx)) << 4));
                vf11 = *(const h8*)(ldsc + bufbase + 8192 + 4096 + rowb
                                    + ((A ^ (2 ^ vx) ^ 4) << 4));
            }
            __builtin_amdgcn_s_setprio(1);
            xacc0 = __builtin_amdgcn_mfma_f32_32x32x16_f16(f0.v, vf00, xacc0, 0, 0, 0);
            xacc1 = __builtin_amdgcn_mfma_f32_32x32x16_f16(f0.v, vf01, xacc1, 0, 0, 0);
            xacc0 = __builtin_amdgcn_mfma_f32_32x32x16_f16(f1.v, vf10, xacc0, 0, 0, 0);
            xacc1 = __builtin_amdgcn_mfma_f32_32x32x16_f16(f1.v, vf11, xacc1, 0, 0, 0);
            __builtin_amdgcn_s_setprio(0);
        }
    };

    // ---- main loop: drain -> barrier -> stage-next -> compute ----
    STAGE(0, kbase);
    for (int t2 = 0; t2 < NTt; ++t2) {
        asm volatile("s_waitcnt vmcnt(0)" ::: "memory");
        __builtin_amdgcn_s_barrier();
        if (t2 + 1 < NTt) STAGE(((t2 + 1) & 1) * 16384, kbase + (t2 + 1) * 64);
        COMPUTE((t2 & 1) * 16384);
    }

    // epilogue: per-wave complete 32x64 output
    #pragma unroll
    for (int r = 0; r < 16; ++r) {
        int q  = (r & 3) + 8 * (r >> 2) + 4 * h;
        int qg = q0 + w * 32 + q;
        if (SPLITS > 1) {
            __half* pp = (__half*)outp + ((size_t)(kq * NBH + bh) * S + qg) * D;
            pp[c31]      = __float2half(xacc0[r]);
            pp[32 + c31] = __float2half(xacc1[r]);
        } else {
            float mq = (float)mask[b * S + qg];
            float x0 = xacc0[r] * mq, x1 = xacc1[r] * mq;
            float ss = x0 * x0 + x1 * x1;
            #pragma unroll
            for (int m = 1; m <= 16; m <<= 1) ss += __shfl_xor(ss, m, 64);
            float sc = rsqrtf(ss + 1e-6f);
            float* op = (float*)outp + ((size_t)bh * S + qg) * D;
            op[c31]      = x0 * sc;
            op[32 + c31] = x1 * sc;
        }
    }
}

// Pass 2: sum fp16 key-split partials, query mask, L2-normalize, fp32 out.
template<int SPLITS>
__global__ __launch_bounds__(256) void combine_norm(const __half* __restrict__ P,
                                                    const int* __restrict__ mask,
                                                    float* __restrict__ out) {
    int t = threadIdx.x;
    int l16 = t & 15;
    size_t row = (size_t)blockIdx.x * 16 + (t >> 4);
    size_t i = row * 64 + l16 * 4;
    float x0 = 0.f, x1 = 0.f, x2 = 0.f, x3 = 0.f;
    #pragma unroll
    for (int k = 0; k < SPLITS; ++k) {
        const __half2* p2 = (const __half2*)(P + (size_t)k * NBH * S * D + i);
        __half2 ab = p2[0], cd = p2[1];
        x0 += __low2float(ab); x1 += __high2float(ab);
        x2 += __low2float(cd); x3 += __high2float(cd);
    }
    int bh = (int)(row >> 11);
    int sidx = (int)(row & 2047);
    int b = bh / 12;
    float mq = (float)mask[b * S + sidx];
    x0 *= mq; x1 *= mq; x2 *= mq; x3 *= mq;
    float ss = x0 * x0 + x1 * x1 + x2 * x2 + x3 * x3;
    #pragma unroll
    for (int m = 1; m <= 8; m <<= 1) ss += __shfl_xor(ss, m, 64);
    float sc = rsqrtf(ss + 1e-6f);
    float4 o = { x0 * sc, x1 * sc, x2 * sc, x3 * sc };
    *(float4*)(out + i) = o;
}

extern "C" void kernel_launch(void* const* d_in, const int* in_sizes, int n_in,
                              void* d_out, int out_size, void* d_ws, size_t ws_size,
                              hipStream_t stream) {
    const float* Q    = (const float*)d_in[0];
    const float* K    = (const float*)d_in[1];
    const float* V    = (const float*)d_in[2];
    const int*   mask = (const int*)d_in[3];
    const int*   hlen = (const int*)d_in[4];
    float*       out  = (float*)d_out;

    __hip_bfloat16* Qn = (__hip_bfloat16*)d_ws;
    __hip_bfloat16* Kn = Qn + (size_t)NBH * S * D;
    __half*         Vt = (__half*)(Kn + (size_t)NBH * S * D);
    __half* Pbuf = (__half*)((char*)d_ws + 3ull * NBH * S * D * 2);  // fp16 partials

    const size_t base_b = 3ull * NBH * S * D * 2;    // Qn + Kn + Vt (18.9 MB)
    const size_t part_h = (size_t)NBH * S * D * 2;   // one fp16 partial buffer

    prep<<<2 * NBH * S / 16 + NBH * 32, 256, 0, stream>>>(Q, K, V, mask, Qn, Kn, Vt);
    if (ws_size >= base_b + 4 * part_h) {            // 44.04 MB (proven budget)
        yoso_main<4><<<NBH * 8 * 4, 512, 0, stream>>>(Qn, Kn, Vt, mask, hlen, Pbuf);
        combine_norm<4><<<NBH * S / 16, 256, 0, stream>>>(Pbuf, mask, out);
    } else if (ws_size >= base_b + 2 * part_h) {
        yoso_main<2><<<NBH * 8 * 2, 512, 0, stream>>>(Qn, Kn, Vt, mask, hlen, Pbuf);
        combine_norm<2><<<NBH * S / 16, 256, 0, stream>>>(Pbuf, mask, out);
    } else {
        yoso_main<1><<<NBH * 8, 512, 0, stream>>>(Qn, Kn, Vt, mask, hlen, out);
    }
}

// Round 16
// 71.232 us; speedup vs baseline: 1.0639x; 1.0639x over previous
//
#include <hip/hip_runtime.h>
#include <hip/hip_bf16.h>
#include <hip/hip_fp16.h>

typedef short bf16x8 __attribute__((ext_vector_type(8)));
typedef _Float16 h8 __attribute__((ext_vector_type(8)));
typedef _Float16 h2v __attribute__((ext_vector_type(2)));
typedef __fp16 fp16x2 __attribute__((ext_vector_type(2)));   // cvt_pkrtz return type
typedef float f32x16 __attribute__((ext_vector_type(16)));
typedef unsigned int uint32;

#define S 2048
#define D 64
#define NBH 24

#define GLOAD16(g, l) __builtin_amdgcn_global_load_lds(                      \
    (const __attribute__((address_space(1))) unsigned int*)(g),              \
    (__attribute__((address_space(3))) unsigned int*)(l), 16, 0, 0)

__device__ __forceinline__ int cvtpk_bf16(float lo, float hi) {
    int r;
    asm("v_cvt_pk_bf16_f32 %0, %1, %2" : "=v"(r) : "v"(lo), "v"(hi));
    return r;
}

// Fused prep (float4-vectorized): L2-normalize Q,K rows (fp32->bf16) + transpose V
// (fp16, key-mask folded in).
__global__ __launch_bounds__(256) void prep(const float* __restrict__ Q,
                                            const float* __restrict__ K,
                                            const float* __restrict__ V,
                                            const int* __restrict__ mask,
                                            __hip_bfloat16* __restrict__ Qn,
                                            __hip_bfloat16* __restrict__ Kn,
                                            __half* __restrict__ Vt) {
    __shared__ float tile[64][65];
    const int NBQK = 2 * NBH * S / 16;            // 6144 norm blocks
    int blk = blockIdx.x;
    int t = threadIdx.x;
    if (blk < NBQK) {
        int l16 = t & 15;
        int row = blk * 16 + (t >> 4);
        int half = row >= NBH * S;
        const float* in = half ? K : Q;
        __hip_bfloat16* out = half ? Kn : Qn;
        row -= half * NBH * S;
        float4 x = *(const float4*)(in + (size_t)row * 64 + l16 * 4);
        float ss = x.x * x.x + x.y * x.y + x.z * x.z + x.w * x.w;
        #pragma unroll
        for (int m = 1; m <= 8; m <<= 1) ss += __shfl_xor(ss, m, 64);
        float sc = rsqrtf(ss + 1e-6f);
        int2 pk = { cvtpk_bf16(x.x * sc, x.y * sc), cvtpk_bf16(x.z * sc, x.w * sc) };
        *(int2*)(out + (size_t)row * 64 + l16 * 4) = pk;
        return;
    }
    blk -= NBQK;                                  // 768 transpose blocks
    int bh = blk >> 5;
    int b  = bh / 12;
    int s0 = (blk & 31) << 6;
    #pragma unroll
    for (int i = 0; i < 16; ++i) {
        int idx = i * 256 + t;
        int sl = idx >> 6, d = idx & 63;
        float mv = (float)mask[b * S + s0 + sl];
        tile[sl][d] = V[(size_t)bh * S * D + (size_t)(s0 + sl) * D + d] * mv;
    }
    __syncthreads();
    #pragma unroll
    for (int i = 0; i < 16; ++i) {
        int idx = i * 256 + t;
        int d = idx >> 6, sl = idx & 63;
        Vt[(size_t)bh * S * D + (size_t)d * S + s0 + sl] = __float2half(tile[sl][d]);
    }
}

// Main: 512-thread blocks (8 waves), block = (bh, 128 q-rows, key-range S/SPLITS).
// 8 waves = 4 q-quarters (qh = w>>1, 32 rows each) x 2 key-halves (kh = w&1).
// Grid = 24 x 16 x SPLITS; SPLITS=4 -> 1536 blocks = 6/CU. With the natural
// ~100-reg/wave cap of 2 blocks/CU, demand is a MULTIPLE of capacity ->
// three full [2,2] rounds, no under-occupied tail (R15 post-mortem: forcing
// 3 blocks/CU via launch_bounds spilled; R12's [2,1] tail was the real cost).
// End-of-kernel LDS reduce combines the kh pair per qh.
// 2-buffer 32KB LDS. SOUND schedule (R7): vmcnt(0) -> s_barrier -> STAGE(next)
// -> COMPUTE(cur). NEVER wait vmcnt after the barrier (vmcnt is per-wave).
// Transform in packed fp16 (v_pk_*_f16); P and V fp16; PV mfma_f32_32x32x16_f16.
// LDS slot(row,u) = u ^ (row&7) ^ (row>>3) ^ ((u&1)<<2) (conflict-free b128);
// stage pre-applies the inverse on the global source address (G21).
template<int SPLITS>
__global__ __launch_bounds__(512) void yoso_main(const __hip_bfloat16* __restrict__ Qn,
                                                 const __hip_bfloat16* __restrict__ Kn,
                                                 const __half* __restrict__ Vt,
                                                 const int* __restrict__ mask,
                                                 const int* __restrict__ hlen_ptr,
                                                 void* __restrict__ outp) {
    __shared__ char lds[2][16384];   // per buf: [0,8192)=K tile, [8192,16384)=V tile

    const int QT = 16;                            // 128-q tiles
    const int blk = blockIdx.x;
    const int bh  = blk / (QT * SPLITS);
    const int rr  = blk % (QT * SPLITS);
    const int q0  = (rr / SPLITS) << 7;
    const int kq  = rr % SPLITS;
    const int kbase = kq * (S / SPLITS);
    const int NTt   = S / SPLITS / 64;

    const int b    = bh / 12;
    const int t    = threadIdx.x;
    const int w    = t >> 6;                      // 0..7
    const int lane = t & 63;
    const int h    = lane >> 5;
    const int c31  = lane & 31;
    const int qh   = w >> 1;                      // q-quarter 0..3
    const int kh   = w & 1;                       // key-half 0..1
    const int hcode = hlen_ptr[0];
    const size_t head = (size_t)bh * S * D;

    // ---- staging source offsets (inverse swizzle on global address) ----
    const int s_  = lane & 7;
    const int r3l = lane >> 3;
    const int e1  = s_ ^ r3l ^ (w & 7);
    const int u1  = e1 ^ ((e1 & 1) << 2);
    const int kgo1 = (8 * w + r3l) * 128 + u1 * 16;
    const int vgo1 = (8 * w + r3l) * 4096 + u1 * 16;
    const char* Kg = (const char*)(Kn + head);   // key-row stride 128 B
    const char* Vg = (const char*)(Vt + head);   // d-row stride 4096 B

    // ---- LDS read offsets for THIS wave's key-half (loop-invariant) ----
    char* ldsc = &lds[0][0];
    int koffs[4], voffs[2][2];
    {
        int krow = kh * 32 + c31;
        int kb3  = (krow & 7) ^ (krow >> 3) ^ (h << 2) ^ h;
        #pragma unroll
        for (int kd = 0; kd < 4; ++kd)
            koffs[kd] = krow * 128 + (((2 * kd) ^ kb3)) * 16;
        int vb3 = (c31 & 7) ^ (c31 >> 3) ^ (h << 2) ^ h ^ (kh << 2);
        #pragma unroll
        for (int kb2 = 0; kb2 < 2; ++kb2) {
            voffs[kb2][0] = c31 * 128        + (((kb2 << 1) ^ vb3)) * 16     + 8192;
            voffs[kb2][1] = (32 + c31) * 128 + (((kb2 << 1) ^ vb3 ^ 4)) * 16 + 8192;
        }
    }

    // Q B-fragments: wave covers q rows q0 + qh*32 + c31
    bf16x8 qf[4];
    {
        const __hip_bfloat16* qp = Qn + head + (size_t)(q0 + qh * 32 + c31) * D + h * 8;
        qf[0] = *(const bf16x8*)(qp);
        qf[1] = *(const bf16x8*)(qp + 16);
        qf[2] = *(const bf16x8*)(qp + 32);
        qf[3] = *(const bf16x8*)(qp + 48);
    }
    asm volatile("" :: "v"(qf[0]), "v"(qf[1]), "v"(qf[2]), "v"(qf[3]));

    const f32x16 z16 = {0,0,0,0,0,0,0,0,0,0,0,0,0,0,0,0};
    f32x16 xacc0 = z16, xacc1 = z16;

    const bool  p9 = (hcode == 9);
    const float hf = (float)hcode;

    // packed fp16 constants (native vector ops -> v_pk_*_f16)
    const h2v one2  = {(_Float16)1.0f,  (_Float16)1.0f};
    const h2v half2 = {(_Float16)0.5f,  (_Float16)0.5f};
    const h2v zero2 = {(_Float16)0.0f,  (_Float16)0.0f};
    const h2v q3c = {(_Float16)-0.00596128f, (_Float16)-0.00596128f};
    const h2v q2c = {(_Float16)-0.00575336f, (_Float16)-0.00575336f};
    const h2v q1c = {(_Float16)-0.03812704f, (_Float16)-0.03812704f};
    const h2v q0c = {(_Float16)-0.4501324f,  (_Float16)-0.4501324f};

    auto STAGE = [&](int base, int k0) {
        const char* kb = Kg + (size_t)k0 * 128;
        const char* vb = Vg + (size_t)k0 * 2;
        char* Kl = ldsc + base;
        char* Vl = Kl + 8192;
        GLOAD16(kb + kgo1, Kl + w * 1024);        // 512 thr x 16B = full 8KB K tile
        GLOAD16(vb + vgo1, Vl + w * 1024);        // full 8KB V tile
    };

    // generic-hcode scalar fallback
    auto XFgen = [&](float s) -> float {
        float z  = fmaxf(1.0f - fabsf(s), 0.0f);
        float qp = ((0.00596128f * z + 0.00575336f) * z + 0.03812704f) * z + 0.4501324f;
        float tp = 0.5f - __builtin_amdgcn_sqrtf(z) * qp;
        float x  = 0.5f + __builtin_copysignf(tp, s);
        return __builtin_amdgcn_exp2f(hf * __builtin_amdgcn_logf(x));
    };

    auto COMPUTE = [&](int bufbase) {
        const char* base = ldsc + bufbase;
        // S^T = K_half @ Q^T : C[row=key][col=q]  (this wave's kh half only)
        __builtin_amdgcn_s_setprio(1);
        f32x16 sacc = __builtin_amdgcn_mfma_f32_32x32x16_bf16(
            *(const bf16x8*)(base + koffs[0]), qf[0], z16, 0, 0, 0);
        #pragma unroll
        for (int kd = 1; kd < 4; ++kd)
            sacc = __builtin_amdgcn_mfma_f32_32x32x16_bf16(
                *(const bf16x8*)(base + koffs[kd]), qf[kd], sacc, 0, 0, 0);
        __builtin_amdgcn_s_setprio(0);

        // w = x^h, x = 0.5 + copysign(0.5 - sqrt(z)*q(z), s), z = 1-|s|
        int u_[8];
        union HU { h2v v; fp16x2 p; uint32 u; };
        if (p9) {
            #pragma unroll
            for (int i = 0; i < 8; ++i) {
                HU cv; cv.p = __builtin_amdgcn_cvt_pkrtz(sacc[2 * i], sacc[2 * i + 1]);
                uint32 spb = cv.u;
                HU za; za.u = spb & 0x7FFF7FFFu;                 // |s|
                h2v z = one2 - za.v;
                z = __builtin_elementwise_max(z, zero2);          // max(1-|s|,0)
                h2v rt = __builtin_elementwise_sqrt(z);
                h2v q = q3c * z + q2c;                            // -q(z) Horner
                q = q * z + q1c;
                q = q * z + q0c;
                HU tb; tb.v = q * rt + half2;                     // 0.5 - q(z)*sqrt(z) >= 0
                HU xb; xb.u = (tb.u & 0x7FFF7FFFu) | (spb & 0x80008000u);
                h2v x = xb.v + half2;                             // 0.5 + copysign(tp, s)
                h2v x2 = x * x;
                h2v x4 = x2 * x2;
                h2v x8 = x4 * x4;
                HU wr; wr.v = x8 * x;                             // x^9, packed fp16
                u_[i] = (int)wr.u;
            }
        } else {
            #pragma unroll
            for (int i = 0; i < 8; ++i) {
                HU cv;
                cv.p = __builtin_amdgcn_cvt_pkrtz(XFgen(sacc[2 * i]),
                                                  XFgen(sacc[2 * i + 1]));
                u_[i] = (int)cv.u;
            }
        }
        asm("v_permlane32_swap_b32 %0, %1" : "+v"(u_[0]), "+v"(u_[2]));
        asm("v_permlane32_swap_b32 %0, %1" : "+v"(u_[1]), "+v"(u_[3]));
        asm("v_permlane32_swap_b32 %0, %1" : "+v"(u_[4]), "+v"(u_[6]));
        asm("v_permlane32_swap_b32 %0, %1" : "+v"(u_[5]), "+v"(u_[7]));
        union { int i[4]; h8 v; } f0, f1;
        f0.i[0] = u_[0]; f0.i[1] = u_[1]; f0.i[2] = u_[2]; f0.i[3] = u_[3];
        f1.i[0] = u_[4]; f1.i[1] = u_[5]; f1.i[2] = u_[6]; f1.i[3] = u_[7];

        // X_half += P_half @ V_half (fp16 MFMA)
        h8 vf00 = *(const h8*)(base + voffs[0][0]);
        h8 vf01 = *(const h8*)(base + voffs[0][1]);
        h8 vf10 = *(const h8*)(base + voffs[1][0]);
        h8 vf11 = *(const h8*)(base + voffs[1][1]);
        __builtin_amdgcn_s_setprio(1);
        xacc0 = __builtin_amdgcn_mfma_f32_32x32x16_f16(f0.v, vf00, xacc0, 0, 0, 0);
        xacc1 = __builtin_amdgcn_mfma_f32_32x32x16_f16(f0.v, vf01, xacc1, 0, 0, 0);
        xacc0 = __builtin_amdgcn_mfma_f32_32x32x16_f16(f1.v, vf10, xacc0, 0, 0, 0);
        xacc1 = __builtin_amdgcn_mfma_f32_32x32x16_f16(f1.v, vf11, xacc1, 0, 0, 0);
        __builtin_amdgcn_s_setprio(0);
    };

    // ---- main loop: drain -> barrier -> stage-next -> compute ----
    STAGE(0, kbase);
    for (int t2 = 0; t2 < NTt; ++t2) {
        asm volatile("s_waitcnt vmcnt(0)" ::: "memory");
        __builtin_amdgcn_s_barrier();
        if (t2 + 1 < NTt) STAGE(((t2 + 1) & 1) * 16384, kbase + (t2 + 1) * 64);
        COMPUTE((t2 & 1) * 16384);
    }

    // ---- cross-wave reduce over key-halves (kh pair per qh), then store ----
    // red[(qh*32+q)*64 + d], 128q x 64d x 4B = 32KB = entire lds array.
    __syncthreads();
    float* red = (float*)ldsc;
    if (kh == 1) {
        #pragma unroll
        for (int r = 0; r < 16; ++r) {
            int q = (r & 3) + 8 * (r >> 2) + 4 * h;
            red[(qh * 32 + q) * 64 + c31]      = xacc0[r];
            red[(qh * 32 + q) * 64 + 32 + c31] = xacc1[r];
        }
    }
    __syncthreads();
    if (kh == 0) {
        #pragma unroll
        for (int r = 0; r < 16; ++r) {
            int q  = (r & 3) + 8 * (r >> 2) + 4 * h;
            int qg = q0 + qh * 32 + q;
            float x0 = xacc0[r] + red[(qh * 32 + q) * 64 + c31];
            float x1 = xacc1[r] + red[(qh * 32 + q) * 64 + 32 + c31];
            if (SPLITS > 1) {
                __half* pp = (__half*)outp + ((size_t)(kq * NBH + bh) * S + qg) * D;
                pp[c31]      = __float2half(x0);
                pp[32 + c31] = __float2half(x1);
            } else {
                float mq = (float)mask[b * S + qg];
                x0 *= mq; x1 *= mq;
                float ss = x0 * x0 + x1 * x1;
                #pragma unroll
                for (int m = 1; m <= 16; m <<= 1) ss += __shfl_xor(ss, m, 64);
                float sc = rsqrtf(ss + 1e-6f);
                float* op = (float*)outp + ((size_t)bh * S + qg) * D;
                op[c31]      = x0 * sc;
                op[32 + c31] = x1 * sc;
            }
        }
    }
}

// Pass 2: sum fp16 key-split partials, query mask, L2-normalize, fp32 out.
template<int SPLITS>
__global__ __launch_bounds__(256) void combine_norm(const __half* __restrict__ P,
                                                    const int* __restrict__ mask,
                                                    float* __restrict__ out) {
    int t = threadIdx.x;
    int l16 = t & 15;
    size_t row = (size_t)blockIdx.x * 16 + (t >> 4);
    size_t i = row * 64 + l16 * 4;
    float x0 = 0.f, x1 = 0.f, x2 = 0.f, x3 = 0.f;
    #pragma unroll
    for (int k = 0; k < SPLITS; ++k) {
        const __half2* p2 = (const __half2*)(P + (size_t)k * NBH * S * D + i);
        __half2 ab = p2[0], cd = p2[1];
        x0 += __low2float(ab); x1 += __high2float(ab);
        x2 += __low2float(cd); x3 += __high2float(cd);
    }
    int bh = (int)(row >> 11);
    int sidx = (int)(row & 2047);
    int b = bh / 12;
    float mq = (float)mask[b * S + sidx];
    x0 *= mq; x1 *= mq; x2 *= mq; x3 *= mq;
    float ss = x0 * x0 + x1 * x1 + x2 * x2 + x3 * x3;
    #pragma unroll
    for (int m = 1; m <= 8; m <<= 1) ss += __shfl_xor(ss, m, 64);
    float sc = rsqrtf(ss + 1e-6f);
    float4 o = { x0 * sc, x1 * sc, x2 * sc, x3 * sc };
    *(float4*)(out + i) = o;
}

extern "C" void kernel_launch(void* const* d_in, const int* in_sizes, int n_in,
                              void* d_out, int out_size, void* d_ws, size_t ws_size,
                              hipStream_t stream) {
    const float* Q    = (const float*)d_in[0];
    const float* K    = (const float*)d_in[1];
    const float* V    = (const float*)d_in[2];
    const int*   mask = (const int*)d_in[3];
    const int*   hlen = (const int*)d_in[4];
    float*       out  = (float*)d_out;

    __hip_bfloat16* Qn = (__hip_bfloat16*)d_ws;
    __hip_bfloat16* Kn = Qn + (size_t)NBH * S * D;
    __half*         Vt = (__half*)(Kn + (size_t)NBH * S * D);
    __half* Pbuf = (__half*)((char*)d_ws + 3ull * NBH * S * D * 2);  // fp16 partials

    const size_t base_b = 3ull * NBH * S * D * 2;    // Qn + Kn + Vt (18.9 MB)
    const size_t part_h = (size_t)NBH * S * D * 2;   // one fp16 partial buffer

    prep<<<2 * NBH * S / 16 + NBH * 32, 256, 0, stream>>>(Q, K, V, mask, Qn, Kn, Vt);
    if (ws_size >= base_b + 4 * part_h) {            // 44.04 MB (proven budget)
        yoso_main<4><<<NBH * 16 * 4, 512, 0, stream>>>(Qn, Kn, Vt, mask, hlen, Pbuf);
        combine_norm<4><<<NBH * S / 16, 256, 0, stream>>>(Pbuf, mask, out);
    } else if (ws_size >= base_b + 2 * part_h) {
        yoso_main<2><<<NBH * 16 * 2, 512, 0, stream>>>(Qn, Kn, Vt, mask, hlen, Pbuf);
        combine_norm<2><<<NBH * S / 16, 256, 0, stream>>>(Pbuf, mask, out);
    } else {
        yoso_main<1><<<NBH * 16, 512, 0, stream>>>(Qn, Kn, Vt, mask, hlen, out);
    }
}

// Round 17
// 69.370 us; speedup vs baseline: 1.0924x; 1.0268x over previous
//
#include <hip/hip_runtime.h>
#include <hip/hip_bf16.h>
#include <hip/hip_fp16.h>

typedef short bf16x8 __attribute__((ext_vector_type(8)));
typedef _Float16 h8 __attribute__((ext_vector_type(8)));
typedef __fp16 fp16x2 __attribute__((ext_vector_type(2)));   // cvt_pkrtz return type
typedef float f32x16 __attribute__((ext_vector_type(16)));
typedef unsigned int uint32;

#define S 2048
#define D 64
#define NBH 24

#define GLOAD16(g, l) __builtin_amdgcn_global_load_lds(                      \
    (const __attribute__((address_space(1))) unsigned int*)(g),              \
    (__attribute__((address_space(3))) unsigned int*)(l), 16, 0, 0)

__device__ __forceinline__ int cvtpk_bf16(float lo, float hi) {
    int r;
    asm("v_cvt_pk_bf16_f32 %0, %1, %2" : "=v"(r) : "v"(lo), "v"(hi));
    return r;
}
__device__ __forceinline__ uint32 pkh(float f) {   // packed fp16 {f,f}
    union { fp16x2 p; uint32 u; } c;
    c.p = __builtin_amdgcn_cvt_pkrtz(f, f);
    return c.u;
}

// Fused prep (float4-vectorized): L2-normalize Q,K rows (fp32->bf16) + transpose V
// (fp16, key-mask folded in).
__global__ __launch_bounds__(256) void prep(const float* __restrict__ Q,
                                            const float* __restrict__ K,
                                            const float* __restrict__ V,
                                            const int* __restrict__ mask,
                                            __hip_bfloat16* __restrict__ Qn,
                                            __hip_bfloat16* __restrict__ Kn,
                                            __half* __restrict__ Vt) {
    __shared__ float tile[64][65];
    const int NBQK = 2 * NBH * S / 16;            // 6144 norm blocks
    int blk = blockIdx.x;
    int t = threadIdx.x;
    if (blk < NBQK) {
        int l16 = t & 15;
        int row = blk * 16 + (t >> 4);
        int half = row >= NBH * S;
        const float* in = half ? K : Q;
        __hip_bfloat16* out = half ? Kn : Qn;
        row -= half * NBH * S;
        float4 x = *(const float4*)(in + (size_t)row * 64 + l16 * 4);
        float ss = x.x * x.x + x.y * x.y + x.z * x.z + x.w * x.w;
        #pragma unroll
        for (int m = 1; m <= 8; m <<= 1) ss += __shfl_xor(ss, m, 64);
        float sc = rsqrtf(ss + 1e-6f);
        int2 pk = { cvtpk_bf16(x.x * sc, x.y * sc), cvtpk_bf16(x.z * sc, x.w * sc) };
        *(int2*)(out + (size_t)row * 64 + l16 * 4) = pk;
        return;
    }
    blk -= NBQK;                                  // 768 transpose blocks
    int bh = blk >> 5;
    int b  = bh / 12;
    int s0 = (blk & 31) << 6;
    #pragma unroll
    for (int i = 0; i < 16; ++i) {
        int idx = i * 256 + t;
        int sl = idx >> 6, d = idx & 63;
        float mv = (float)mask[b * S + s0 + sl];
        tile[sl][d] = V[(size_t)bh * S * D + (size_t)(s0 + sl) * D + d] * mv;
    }
    __syncthreads();
    #pragma unroll
    for (int i = 0; i < 16; ++i) {
        int idx = i * 256 + t;
        int d = idx >> 6, sl = idx & 63;
        Vt[(size_t)bh * S * D + (size_t)d * S + s0 + sl] = __float2half(tile[sl][d]);
    }
}

// Main (R12 structure, best measured = 53us): 512-thread blocks (8 waves),
// block = (bh, 256 q-rows, key-range S/SPLITS). Grid = 24 x 8 x SPLITS.
// Each wave owns 32 q-rows and covers BOTH 32-key halves of each 64-key tile.
// 2-buffer 32KB LDS. SOUND schedule (R7 post-mortem): per tile
//   vmcnt(0) [own loads, issued one COMPUTE ago] -> s_barrier [cross-wave
//   publish] -> STAGE(next buf) [WAR-safe] -> COMPUTE(cur).
// NEVER wait vmcnt AFTER the barrier: vmcnt is per-wave.
// Transform: explicit VOP3P inline asm (guaranteed packed, 18 ops/pair):
//   cvt_pkrtz, or(sign-force -> -|s|), pk_add(1-|s|), pk_max(,0), lshr +
//   2x v_sqrt_f16 + v_pack_b32_f16, 4x pk_fma (Horner+tp), v_bfi(copysign),
//   pk_add(+0.5), 4x pk_mul (x^9). P and V fp16; PV mfma_f32_32x32x16_f16.
// LDS slot(row,u) = u ^ (row&7) ^ (row>>3) ^ ((u&1)<<2) (conflict-free b128);
// stage pre-applies the inverse on the global source address (G21).
template<int SPLITS>
__global__ __launch_bounds__(512) void yoso_main(const __hip_bfloat16* __restrict__ Qn,
                                                 const __hip_bfloat16* __restrict__ Kn,
                                                 const __half* __restrict__ Vt,
                                                 const int* __restrict__ mask,
                                                 const int* __restrict__ hlen_ptr,
                                                 void* __restrict__ outp) {
    __shared__ char lds[2][16384];   // per buf: [0,8192)=K tile, [8192,16384)=V tile

    const int QT = 8;                             // 256-q tiles
    const int blk = blockIdx.x;
    const int bh  = blk / (QT * SPLITS);
    const int rr  = blk % (QT * SPLITS);
    const int q0  = (rr / SPLITS) << 8;
    const int kq  = rr % SPLITS;
    const int kbase = kq * (S / SPLITS);
    const int NTt   = S / SPLITS / 64;

    const int b    = bh / 12;
    const int t    = threadIdx.x;
    const int w    = t >> 6;                      // 0..7
    const int lane = t & 63;
    const int h    = lane >> 5;
    const int c31  = lane & 31;
    const int hcode = hlen_ptr[0];
    const size_t head = (size_t)bh * S * D;

    // ---- staging source offsets (inverse swizzle on global address) ----
    const int s_  = lane & 7;
    const int r3l = lane >> 3;
    const int e1  = s_ ^ r3l ^ (w & 7);
    const int u1  = e1 ^ ((e1 & 1) << 2);
    const int kgo1 = (8 * w + r3l) * 128 + u1 * 16;
    const int vgo1 = (8 * w + r3l) * 4096 + u1 * 16;
    const char* Kg = (const char*)(Kn + head);   // key-row stride 128 B
    const char* Vg = (const char*)(Vt + head);   // d-row stride 4096 B

    // ---- LDS read offsets per key-half (loop-invariant, wave-independent) ----
    char* ldsc = &lds[0][0];
    int koffs[2][4], voffs[2][2][2];
    #pragma unroll
    for (int kh2 = 0; kh2 < 2; ++kh2) {
        int krow = kh2 * 32 + c31;
        int kb3  = (krow & 7) ^ (krow >> 3) ^ (h << 2) ^ h;
        #pragma unroll
        for (int kd = 0; kd < 4; ++kd)
            koffs[kh2][kd] = krow * 128 + (((2 * kd) ^ kb3)) * 16;
        int vb3 = (c31 & 7) ^ (c31 >> 3) ^ (h << 2) ^ h ^ (kh2 << 2);
        #pragma unroll
        for (int kb2 = 0; kb2 < 2; ++kb2) {
            voffs[kh2][kb2][0] = c31 * 128        + (((kb2 << 1) ^ vb3)) * 16     + 8192;
            voffs[kh2][kb2][1] = (32 + c31) * 128 + (((kb2 << 1) ^ vb3 ^ 4)) * 16 + 8192;
        }
    }

    // Q B-fragments: wave w owns q rows q0 + w*32 + c31
    bf16x8 qf[4];
    {
        const __hip_bfloat16* qp = Qn + head + (size_t)(q0 + w * 32 + c31) * D + h * 8;
        qf[0] = *(const bf16x8*)(qp);
        qf[1] = *(const bf16x8*)(qp + 16);
        qf[2] = *(const bf16x8*)(qp + 32);
        qf[3] = *(const bf16x8*)(qp + 48);
    }
    asm volatile("" :: "v"(qf[0]), "v"(qf[1]), "v"(qf[2]), "v"(qf[3]));

    const f32x16 z16 = {0,0,0,0,0,0,0,0,0,0,0,0,0,0,0,0};
    f32x16 xacc0 = z16, xacc1 = z16;

    const bool  p9 = (hcode == 9);
    const float hf = (float)hcode;

    // packed fp16 constants (one-time)
    const uint32 ONE2  = pkh(1.0f);
    const uint32 HALF2 = pkh(0.5f);
    const uint32 Q3    = pkh(-0.00596128f);   // -q(z) Horner coeffs
    const uint32 Q2    = pkh(-0.00575336f);
    const uint32 Q1    = pkh(-0.03812704f);
    const uint32 Q0    = pkh(-0.4501324f);
    const uint32 MAGM  = 0x7FFF7FFFu;

    auto STAGE = [&](int base, int k0) {
        const char* kb = Kg + (size_t)k0 * 128;
        const char* vb = Vg + (size_t)k0 * 2;
        char* Kl = ldsc + base;
        char* Vl = Kl + 8192;
        GLOAD16(kb + kgo1, Kl + w * 1024);        // 512 thr x 16B = full 8KB K tile
        GLOAD16(vb + vgo1, Vl + w * 1024);        // full 8KB V tile
    };

    // generic-hcode scalar fallback
    auto XFgen = [&](float s) -> float {
        float z  = fmaxf(1.0f - fabsf(s), 0.0f);
        float qp = ((0.00596128f * z + 0.00575336f) * z + 0.03812704f) * z + 0.4501324f;
        float tp = 0.5f - __builtin_amdgcn_sqrtf(z) * qp;
        float x  = 0.5f + __builtin_copysignf(tp, s);
        return __builtin_amdgcn_exp2f(hf * __builtin_amdgcn_logf(x));
    };

    // explicit-packed transform: 2 elems -> packed fp16 w = x^9 (18 VALU ops)
    auto XF2 = [&](float s0, float s1) -> uint32 {
        uint32 sp, z, zc, rlo, rhi, rt, q, tp, xb, x, x2, x4, x8, wv;
        asm("v_cvt_pkrtz_f16_f32 %0, %1, %2" : "=v"(sp) : "v"(s0), "v"(s1));
        uint32 nabs = sp | 0x80008000u;                       // -|s| (sign forced)
        asm("v_pk_add_f16 %0, %1, %2" : "=v"(z)  : "v"(ONE2), "v"(nabs)); // 1-|s|
        asm("v_pk_max_f16 %0, %1, 0"  : "=v"(zc) : "v"(z));               // clamp >= 0
        uint32 zh = zc >> 16;
        asm("v_sqrt_f16 %0, %1" : "=v"(rlo) : "v"(zc));
        asm("v_sqrt_f16 %0, %1" : "=v"(rhi) : "v"(zh));
        asm("v_pack_b32_f16 %0, %1, %2" : "=v"(rt) : "v"(rlo), "v"(rhi));
        asm("v_pk_fma_f16 %0, %1, %2, %3" : "=v"(q)  : "v"(Q3), "v"(zc), "v"(Q2));
        asm("v_pk_fma_f16 %0, %1, %2, %3" : "=v"(q)  : "v"(q),  "v"(zc), "v"(Q1));
        asm("v_pk_fma_f16 %0, %1, %2, %3" : "=v"(q)  : "v"(q),  "v"(zc), "v"(Q0));
        asm("v_pk_fma_f16 %0, %1, %2, %3" : "=v"(tp) : "v"(q),  "v"(rt), "v"(HALF2));
        asm("v_bfi_b32 %0, %1, %2, %3" : "=v"(xb) : "v"(MAGM), "v"(tp), "v"(sp));
        asm("v_pk_add_f16 %0, %1, %2" : "=v"(x)  : "v"(xb), "v"(HALF2));  // 0.5+copysign
        asm("v_pk_mul_f16 %0, %1, %1" : "=v"(x2) : "v"(x));
        asm("v_pk_mul_f16 %0, %1, %1" : "=v"(x4) : "v"(x2));
        asm("v_pk_mul_f16 %0, %1, %1" : "=v"(x8) : "v"(x4));
        asm("v_pk_mul_f16 %0, %1, %2" : "=v"(wv) : "v"(x8), "v"(x));      // x^9
        return wv;
    };

    auto COMPUTE = [&](int bufbase) {
        const char* base = ldsc + bufbase;
        #pragma unroll
        for (int kh2 = 0; kh2 < 2; ++kh2) {
            // S^T = K_half @ Q^T : C[row=key][col=q]
            __builtin_amdgcn_s_setprio(1);
            f32x16 sacc = __builtin_amdgcn_mfma_f32_32x32x16_bf16(
                *(const bf16x8*)(base + koffs[kh2][0]), qf[0], z16, 0, 0, 0);
            #pragma unroll
            for (int kd = 1; kd < 4; ++kd)
                sacc = __builtin_amdgcn_mfma_f32_32x32x16_bf16(
                    *(const bf16x8*)(base + koffs[kh2][kd]), qf[kd], sacc, 0, 0, 0);
            __builtin_amdgcn_s_setprio(0);

            int u_[8];
            if (p9) {
                #pragma unroll
                for (int i = 0; i < 8; ++i)
                    u_[i] = (int)XF2(sacc[2 * i], sacc[2 * i + 1]);
            } else {
                #pragma unroll
                for (int i = 0; i < 8; ++i) {
                    union { fp16x2 p; uint32 u; } cv;
                    cv.p = __builtin_amdgcn_cvt_pkrtz(XFgen(sacc[2 * i]),
                                                      XFgen(sacc[2 * i + 1]));
                    u_[i] = (int)cv.u;
                }
            }
            asm("v_permlane32_swap_b32 %0, %1" : "+v"(u_[0]), "+v"(u_[2]));
            asm("v_permlane32_swap_b32 %0, %1" : "+v"(u_[1]), "+v"(u_[3]));
            asm("v_permlane32_swap_b32 %0, %1" : "+v"(u_[4]), "+v"(u_[6]));
            asm("v_permlane32_swap_b32 %0, %1" : "+v"(u_[5]), "+v"(u_[7]));
            union { int i[4]; h8 v; } f0, f1;
            f0.i[0] = u_[0]; f0.i[1] = u_[1]; f0.i[2] = u_[2]; f0.i[3] = u_[3];
            f1.i[0] = u_[4]; f1.i[1] = u_[5]; f1.i[2] = u_[6]; f1.i[3] = u_[7];

            // X += P_half @ V_half (fp16 MFMA; fragment layout dtype-independent)
            h8 vf00 = *(const h8*)(base + voffs[kh2][0][0]);
            h8 vf01 = *(const h8*)(base + voffs[kh2][0][1]);
            h8 vf10 = *(const h8*)(base + voffs[kh2][1][0]);
            h8 vf11 = *(const h8*)(base + voffs[kh2][1][1]);
            __builtin_amdgcn_s_setprio(1);
            xacc0 = __builtin_amdgcn_mfma_f32_32x32x16_f16(f0.v, vf00, xacc0, 0, 0, 0);
            xacc1 = __builtin_amdgcn_mfma_f32_32x32x16_f16(f0.v, vf01, xacc1, 0, 0, 0);
            xacc0 = __builtin_amdgcn_mfma_f32_32x32x16_f16(f1.v, vf10, xacc0, 0, 0, 0);
            xacc1 = __builtin_amdgcn_mfma_f32_32x32x16_f16(f1.v, vf11, xacc1, 0, 0, 0);
            __builtin_amdgcn_s_setprio(0);
        }
    };

    // ---- main loop: drain -> barrier -> stage-next -> compute ----
    STAGE(0, kbase);
    for (int t2 = 0; t2 < NTt; ++t2) {
        asm volatile("s_waitcnt vmcnt(0)" ::: "memory");
        __builtin_amdgcn_s_barrier();
        if (t2 + 1 < NTt) STAGE(((t2 + 1) & 1) * 16384, kbase + (t2 + 1) * 64);
        COMPUTE((t2 & 1) * 16384);
    }

    // epilogue: per-wave complete 32x64 output
    #pragma unroll
    for (int r = 0; r < 16; ++r) {
        int q  = (r & 3) + 8 * (r >> 2) + 4 * h;
        int qg = q0 + w * 32 + q;
        if (SPLITS > 1) {
            __half* pp = (__half*)outp + ((size_t)(kq * NBH + bh) * S + qg) * D;
            pp[c31]      = __float2half(xacc0[r]);
            pp[32 + c31] = __float2half(xacc1[r]);
        } else {
            float mq = (float)mask[b * S + qg];
            float x0 = xacc0[r] * mq, x1 = xacc1[r] * mq;
            float ss = x0 * x0 + x1 * x1;
            #pragma unroll
            for (int m = 1; m <= 16; m <<= 1) ss += __shfl_xor(ss, m, 64);
            float sc = rsqrtf(ss + 1e-6f);
            float* op = (float*)outp + ((size_t)bh * S + qg) * D;
            op[c31]      = x0 * sc;
            op[32 + c31] = x1 * sc;
        }
    }
}

// Pass 2: sum fp16 key-split partials, query mask, L2-normalize, fp32 out.
template<int SPLITS>
__global__ __launch_bounds__(256) void combine_norm(const __half* __restrict__ P,
                                                    const int* __restrict__ mask,
                                                    float* __restrict__ out) {
    int t = threadIdx.x;
    int l16 = t & 15;
    size_t row = (size_t)blockIdx.x * 16 + (t >> 4);
    size_t i = row * 64 + l16 * 4;
    float x0 = 0.f, x1 = 0.f, x2 = 0.f, x3 = 0.f;
    #pragma unroll
    for (int k = 0; k < SPLITS; ++k) {
        const __half2* p2 = (const __half2*)(P + (size_t)k * NBH * S * D + i);
        __half2 ab = p2[0], cd = p2[1];
        x0 += __low2float(ab); x1 += __high2float(ab);
        x2 += __low2float(cd); x3 += __high2float(cd);
    }
    int bh = (int)(row >> 11);
    int sidx = (int)(row & 2047);
    int b = bh / 12;
    float mq = (float)mask[b * S + sidx];
    x0 *= mq; x1 *= mq; x2 *= mq; x3 *= mq;
    float ss = x0 * x0 + x1 * x1 + x2 * x2 + x3 * x3;
    #pragma unroll
    for (int m = 1; m <= 8; m <<= 1) ss += __shfl_xor(ss, m, 64);
    float sc = rsqrtf(ss + 1e-6f);
    float4 o = { x0 * sc, x1 * sc, x2 * sc, x3 * sc };
    *(float4*)(out + i) = o;
}

extern "C" void kernel_launch(void* const* d_in, const int* in_sizes, int n_in,
                              void* d_out, int out_size, void* d_ws, size_t ws_size,
                              hipStream_t stream) {
    const float* Q    = (const float*)d_in[0];
    const float* K    = (const float*)d_in[1];
    const float* V    = (const float*)d_in[2];
    const int*   mask = (const int*)d_in[3];
    const int*   hlen = (const int*)d_in[4];
    float*       out  = (float*)d_out;

    __hip_bfloat16* Qn = (__hip_bfloat16*)d_ws;
    __hip_bfloat16* Kn = Qn + (size_t)NBH * S * D;
    __half*         Vt = (__half*)(Kn + (size_t)NBH * S * D);
    __half* Pbuf = (__half*)((char*)d_ws + 3ull * NBH * S * D * 2);  // fp16 partials

    const size_t base_b = 3ull * NBH * S * D * 2;    // Qn + Kn + Vt (18.9 MB)
    const size_t part_h = (size_t)NBH * S * D * 2;   // one fp16 partial buffer

    prep<<<2 * NBH * S / 16 + NBH * 32, 256, 0, stream>>>(Q, K, V, mask, Qn, Kn, Vt);
    if (ws_size >= base_b + 4 * part_h) {            // 44.04 MB (proven budget)
        yoso_main<4><<<NBH * 8 * 4, 512, 0, stream>>>(Qn, Kn, Vt, mask, hlen, Pbuf);
        combine_norm<4><<<NBH * S / 16, 256, 0, stream>>>(Pbuf, mask, out);
    } else if (ws_size >= base_b + 2 * part_h) {
        yoso_main<2><<<NBH * 8 * 2, 512, 0, stream>>>(Qn, Kn, Vt, mask, hlen, Pbuf);
        combine_norm<2><<<NBH * S / 16, 256, 0, stream>>>(Pbuf, mask, out);
    } else {
        yoso_main<1><<<NBH * 8, 512, 0, stream>>>(Qn, Kn, Vt, mask, hlen, out);
    }
}

// Round 18
// 67.438 us; speedup vs baseline: 1.1237x; 1.0286x over previous
//
#include <hip/hip_runtime.h>
#include <hip/hip_bf16.h>
#include <hip/hip_fp16.h>

typedef short bf16x8 __attribute__((ext_vector_type(8)));
typedef _Float16 h8 __attribute__((ext_vector_type(8)));
typedef _Float16 h2v __attribute__((ext_vector_type(2)));
typedef __fp16 fp16x2 __attribute__((ext_vector_type(2)));   // cvt_pkrtz return type
typedef float f32x16 __attribute__((ext_vector_type(16)));
typedef unsigned int uint32;

#define S 2048
#define D 64
#define NBH 24

#define GLOAD16(g, l) __builtin_amdgcn_global_load_lds(                      \
    (const __attribute__((address_space(1))) unsigned int*)(g),              \
    (__attribute__((address_space(3))) unsigned int*)(l), 16, 0, 0)

__device__ __forceinline__ int cvtpk_bf16(float lo, float hi) {
    int r;
    asm("v_cvt_pk_bf16_f32 %0, %1, %2" : "=v"(r) : "v"(lo), "v"(hi));
    return r;
}

// Fused prep (float4-vectorized): L2-normalize Q,K rows (fp32->bf16) + transpose V
// (fp16, key-mask folded in).
__global__ __launch_bounds__(256) void prep(const float* __restrict__ Q,
                                            const float* __restrict__ K,
                                            const float* __restrict__ V,
                                            const int* __restrict__ mask,
                                            __hip_bfloat16* __restrict__ Qn,
                                            __hip_bfloat16* __restrict__ Kn,
                                            __half* __restrict__ Vt) {
    __shared__ float tile[64][65];
    const int NBQK = 2 * NBH * S / 16;            // 6144 norm blocks
    int blk = blockIdx.x;
    int t = threadIdx.x;
    if (blk < NBQK) {
        int l16 = t & 15;
        int row = blk * 16 + (t >> 4);
        int half = row >= NBH * S;
        const float* in = half ? K : Q;
        __hip_bfloat16* out = half ? Kn : Qn;
        row -= half * NBH * S;
        float4 x = *(const float4*)(in + (size_t)row * 64 + l16 * 4);
        float ss = x.x * x.x + x.y * x.y + x.z * x.z + x.w * x.w;
        #pragma unroll
        for (int m = 1; m <= 8; m <<= 1) ss += __shfl_xor(ss, m, 64);
        float sc = rsqrtf(ss + 1e-6f);
        int2 pk = { cvtpk_bf16(x.x * sc, x.y * sc), cvtpk_bf16(x.z * sc, x.w * sc) };
        *(int2*)(out + (size_t)row * 64 + l16 * 4) = pk;
        return;
    }
    blk -= NBQK;                                  // 768 transpose blocks
    int bh = blk >> 5;
    int b  = bh / 12;
    int s0 = (blk & 31) << 6;
    #pragma unroll
    for (int i = 0; i < 16; ++i) {
        int idx = i * 256 + t;
        int sl = idx >> 6, d = idx & 63;
        float mv = (float)mask[b * S + s0 + sl];
        tile[sl][d] = V[(size_t)bh * S * D + (size_t)(s0 + sl) * D + d] * mv;
    }
    __syncthreads();
    #pragma unroll
    for (int i = 0; i < 16; ++i) {
        int idx = i * 256 + t;
        int d = idx >> 6, sl = idx & 63;
        Vt[(size_t)bh * S * D + (size_t)d * S + s0 + sl] = __float2half(tile[sl][d]);
    }
}

// Main (R12 structure + 2-tile phases): 512-thread blocks (8 waves),
// block = (bh, 256 q-rows, key-range S/SPLITS). Grid = 24 x 8 x SPLITS.
// Each wave owns 32 q-rows and covers BOTH 32-key halves of each 64-key tile.
// 4-buffer 64KB LDS, TWO tiles per barrier phase (R17 post-mortem: per-tile
// barriers phase-lock all waves into the same dependent-chain stretch; two
// independent tile-chains per phase double ILP and halve barrier count).
// Phase schedule (sound per R7 rules): vmcnt(0) [drains stages issued last
// phase] -> s_barrier [cross-wave publish] -> STAGE(t+2)+STAGE(t+3) [WAR-safe:
// those buffers were computed last phase, all waves passed the barrier] ->
// COMPUTE(t)+COMPUTE(t+1). NEVER wait vmcnt after the barrier (per-wave ctr).
// Transform in packed fp16 via native _Float16 vector ops (v_pk_*_f16); P and V
// fp16, PV uses mfma_f32_32x32x16_f16 (fragment layout dtype-independent).
// LDS slot(row,u) = u ^ (row&7) ^ (row>>3) ^ ((u&1)<<2) (conflict-free b128,
// both lane phasings); stage pre-applies the inverse on the global source (G21).
template<int SPLITS>
__global__ __launch_bounds__(512) void yoso_main(const __hip_bfloat16* __restrict__ Qn,
                                                 const __hip_bfloat16* __restrict__ Kn,
                                                 const __half* __restrict__ Vt,
                                                 const int* __restrict__ mask,
                                                 const int* __restrict__ hlen_ptr,
                                                 void* __restrict__ outp) {
    __shared__ char lds[4][16384];   // per buf: [0,8192)=K tile, [8192,16384)=V tile

    const int QT = 8;                             // 256-q tiles
    const int blk = blockIdx.x;
    const int bh  = blk / (QT * SPLITS);
    const int rr  = blk % (QT * SPLITS);
    const int q0  = (rr / SPLITS) << 8;
    const int kq  = rr % SPLITS;
    const int kbase = kq * (S / SPLITS);
    const int NTt   = S / SPLITS / 64;            // even for all SPLITS

    const int b    = bh / 12;
    const int t    = threadIdx.x;
    const int w    = t >> 6;                      // 0..7
    const int lane = t & 63;
    const int h    = lane >> 5;
    const int c31  = lane & 31;
    const int hcode = hlen_ptr[0];
    const size_t head = (size_t)bh * S * D;

    // ---- staging source offsets (inverse swizzle on global address) ----
    const int s_  = lane & 7;
    const int r3l = lane >> 3;
    const int e1  = s_ ^ r3l ^ (w & 7);
    const int u1  = e1 ^ ((e1 & 1) << 2);
    const int kgo1 = (8 * w + r3l) * 128 + u1 * 16;
    const int vgo1 = (8 * w + r3l) * 4096 + u1 * 16;
    const char* Kg = (const char*)(Kn + head);   // key-row stride 128 B
    const char* Vg = (const char*)(Vt + head);   // d-row stride 4096 B

    // ---- LDS read offsets per key-half (loop-invariant, wave-independent) ----
    char* ldsc = &lds[0][0];
    int koffs[2][4], voffs[2][2][2];
    #pragma unroll
    for (int kh2 = 0; kh2 < 2; ++kh2) {
        int krow = kh2 * 32 + c31;
        int kb3  = (krow & 7) ^ (krow >> 3) ^ (h << 2) ^ h;
        #pragma unroll
        for (int kd = 0; kd < 4; ++kd)
            koffs[kh2][kd] = krow * 128 + (((2 * kd) ^ kb3)) * 16;
        int vb3 = (c31 & 7) ^ (c31 >> 3) ^ (h << 2) ^ h ^ (kh2 << 2);
        #pragma unroll
        for (int kb2 = 0; kb2 < 2; ++kb2) {
            voffs[kh2][kb2][0] = c31 * 128        + (((kb2 << 1) ^ vb3)) * 16     + 8192;
            voffs[kh2][kb2][1] = (32 + c31) * 128 + (((kb2 << 1) ^ vb3 ^ 4)) * 16 + 8192;
        }
    }

    // Q B-fragments: wave w owns q rows q0 + w*32 + c31
    bf16x8 qf[4];
    {
        const __hip_bfloat16* qp = Qn + head + (size_t)(q0 + w * 32 + c31) * D + h * 8;
        qf[0] = *(const bf16x8*)(qp);
        qf[1] = *(const bf16x8*)(qp + 16);
        qf[2] = *(const bf16x8*)(qp + 32);
        qf[3] = *(const bf16x8*)(qp + 48);
    }
    asm volatile("" :: "v"(qf[0]), "v"(qf[1]), "v"(qf[2]), "v"(qf[3]));

    const f32x16 z16 = {0,0,0,0,0,0,0,0,0,0,0,0,0,0,0,0};
    f32x16 xacc0 = z16, xacc1 = z16;

    const bool  p9 = (hcode == 9);
    const float hf = (float)hcode;

    // packed fp16 constants (native vector ops -> v_pk_*_f16)
    const h2v one2  = {(_Float16)1.0f,  (_Float16)1.0f};
    const h2v half2 = {(_Float16)0.5f,  (_Float16)0.5f};
    const h2v zero2 = {(_Float16)0.0f,  (_Float16)0.0f};
    const h2v q3c = {(_Float16)-0.00596128f, (_Float16)-0.00596128f};
    const h2v q2c = {(_Float16)-0.00575336f, (_Float16)-0.00575336f};
    const h2v q1c = {(_Float16)-0.03812704f, (_Float16)-0.03812704f};
    const h2v q0c = {(_Float16)-0.4501324f,  (_Float16)-0.4501324f};

    auto STAGE = [&](int buf, int k0) {
        const char* kb = Kg + (size_t)k0 * 128;
        const char* vb = Vg + (size_t)k0 * 2;
        char* Kl = ldsc + buf * 16384;
        char* Vl = Kl + 8192;
        GLOAD16(kb + kgo1, Kl + w * 1024);        // 512 thr x 16B = full 8KB K tile
        GLOAD16(vb + vgo1, Vl + w * 1024);        // full 8KB V tile
    };

    // generic-hcode scalar fallback
    auto XFgen = [&](float s) -> float {
        float z  = fmaxf(1.0f - fabsf(s), 0.0f);
        float qp = ((0.00596128f * z + 0.00575336f) * z + 0.03812704f) * z + 0.4501324f;
        float tp = 0.5f - __builtin_amdgcn_sqrtf(z) * qp;
        float x  = 0.5f + __builtin_copysignf(tp, s);
        return __builtin_amdgcn_exp2f(hf * __builtin_amdgcn_logf(x));
    };

    auto COMPUTE = [&](int buf) {
        const char* base = ldsc + buf * 16384;
        #pragma unroll
        for (int kh2 = 0; kh2 < 2; ++kh2) {
            // S^T = K_half @ Q^T : C[row=key][col=q]
            __builtin_amdgcn_s_setprio(1);
            f32x16 sacc = __builtin_amdgcn_mfma_f32_32x32x16_bf16(
                *(const bf16x8*)(base + koffs[kh2][0]), qf[0], z16, 0, 0, 0);
            #pragma unroll
            for (int kd = 1; kd < 4; ++kd)
                sacc = __builtin_amdgcn_mfma_f32_32x32x16_bf16(
                    *(const bf16x8*)(base + koffs[kh2][kd]), qf[kd], sacc, 0, 0, 0);
            __builtin_amdgcn_s_setprio(0);

            // w = x^h, x = 0.5 + copysign(0.5 - sqrt(z)*q(z), s), z = 1-|s|
            // packed fp16: 2 elems per op, sign bits ride along in the pack.
            int u_[8];
            union HU { h2v v; fp16x2 p; uint32 u; };
            if (p9) {
                #pragma unroll
                for (int i = 0; i < 8; ++i) {
                    HU cv; cv.p = __builtin_amdgcn_cvt_pkrtz(sacc[2 * i], sacc[2 * i + 1]);
                    uint32 spb = cv.u;
                    HU za; za.u = spb & 0x7FFF7FFFu;                 // |s|
                    h2v z = one2 - za.v;
                    z = __builtin_elementwise_max(z, zero2);          // max(1-|s|,0)
                    h2v rt = __builtin_elementwise_sqrt(z);
                    h2v q = q3c * z + q2c;                            // -q(z) Horner
                    q = q * z + q1c;
                    q = q * z + q0c;
                    HU tb; tb.v = q * rt + half2;                     // 0.5 - q(z)*sqrt(z) >= 0
                    HU xb; xb.u = (tb.u & 0x7FFF7FFFu) | (spb & 0x80008000u);
                    h2v x = xb.v + half2;                             // 0.5 + copysign(tp, s)
                    h2v x2 = x * x;
                    h2v x4 = x2 * x2;
                    h2v x8 = x4 * x4;
                    HU wr; wr.v = x8 * x;                             // x^9, packed fp16
                    u_[i] = (int)wr.u;
                }
            } else {
                #pragma unroll
                for (int i = 0; i < 8; ++i) {
                    HU cv;
                    cv.p = __builtin_amdgcn_cvt_pkrtz(XFgen(sacc[2 * i]),
                                                      XFgen(sacc[2 * i + 1]));
                    u_[i] = (int)cv.u;
                }
            }
            asm("v_permlane32_swap_b32 %0, %1" : "+v"(u_[0]), "+v"(u_[2]));
            asm("v_permlane32_swap_b32 %0, %1" : "+v"(u_[1]), "+v"(u_[3]));
            asm("v_permlane32_swap_b32 %0, %1" : "+v"(u_[4]), "+v"(u_[6]));
            asm("v_permlane32_swap_b32 %0, %1" : "+v"(u_[5]), "+v"(u_[7]));
            union { int i[4]; h8 v; } f0, f1;
            f0.i[0] = u_[0]; f0.i[1] = u_[1]; f0.i[2] = u_[2]; f0.i[3] = u_[3];
            f1.i[0] = u_[4]; f1.i[1] = u_[5]; f1.i[2] = u_[6]; f1.i[3] = u_[7];

            // X += P_half @ V_half (fp16 MFMA; fragment layout dtype-independent)
            h8 vf00 = *(const h8*)(base + voffs[kh2][0][0]);
            h8 vf01 = *(const h8*)(base + voffs[kh2][0][1]);
            h8 vf10 = *(const h8*)(base + voffs[kh2][1][0]);
            h8 vf11 = *(const h8*)(base + voffs[kh2][1][1]);
            __builtin_amdgcn_s_setprio(1);
            xacc0 = __builtin_amdgcn_mfma_f32_32x32x16_f16(f0.v, vf00, xacc0, 0, 0, 0);
            xacc1 = __builtin_amdgcn_mfma_f32_32x32x16_f16(f0.v, vf01, xacc1, 0, 0, 0);
            xacc0 = __builtin_amdgcn_mfma_f32_32x32x16_f16(f1.v, vf10, xacc0, 0, 0, 0);
            xacc1 = __builtin_amdgcn_mfma_f32_32x32x16_f16(f1.v, vf11, xacc1, 0, 0, 0);
            __builtin_amdgcn_s_setprio(0);
        }
    };

    // ---- main loop: 2 tiles per phase, 4-buffer rotation ----
    STAGE(0, kbase);
    STAGE(1, kbase + 64);
    for (int t2 = 0; t2 < NTt; t2 += 2) {
        asm volatile("s_waitcnt vmcnt(0)" ::: "memory");
        __builtin_amdgcn_s_barrier();
        if (t2 + 2 < NTt) {
            STAGE((t2 + 2) & 3, kbase + (t2 + 2) * 64);
            STAGE((t2 + 3) & 3, kbase + (t2 + 3) * 64);
        }
        COMPUTE(t2 & 3);
        COMPUTE((t2 + 1) & 3);
    }

    // epilogue: per-wave complete 32x64 output
    #pragma unroll
    for (int r = 0; r < 16; ++r) {
        int q  = (r & 3) + 8 * (r >> 2) + 4 * h;
        int qg = q0 + w * 32 + q;
        if (SPLITS > 1) {
            __half* pp = (__half*)outp + ((size_t)(kq * NBH + bh) * S + qg) * D;
            pp[c31]      = __float2half(xacc0[r]);
            pp[32 + c31] = __float2half(xacc1[r]);
        } else {
            float mq = (float)mask[b * S + qg];
            float x0 = xacc0[r] * mq, x1 = xacc1[r] * mq;
            float ss = x0 * x0 + x1 * x1;
            #pragma unroll
            for (int m = 1; m <= 16; m <<= 1) ss += __shfl_xor(ss, m, 64);
            float sc = rsqrtf(ss + 1e-6f);
            float* op = (float*)outp + ((size_t)bh * S + qg) * D;
            op[c31]      = x0 * sc;
            op[32 + c31] = x1 * sc;
        }
    }
}

// Pass 2: sum fp16 key-split partials, query mask, L2-normalize, fp32 out.
template<int SPLITS>
__global__ __launch_bounds__(256) void combine_norm(const __half* __restrict__ P,
                                                    const int* __restrict__ mask,
                                                    float* __restrict__ out) {
    int t = threadIdx.x;
    int l16 = t & 15;
    size_t row = (size_t)blockIdx.x * 16 + (t >> 4);
    size_t i = row * 64 + l16 * 4;
    float x0 = 0.f, x1 = 0.f, x2 = 0.f, x3 = 0.f;
    #pragma unroll
    for (int k = 0; k < SPLITS; ++k) {
        const __half2* p2 = (const __half2*)(P + (size_t)k * NBH * S * D + i);
        __half2 ab = p2[0], cd = p2[1];
        x0 += __low2float(ab); x1 += __high2float(ab);
        x2 += __low2float(cd); x3 += __high2float(cd);
    }
    int bh = (int)(row >> 11);
    int sidx = (int)(row & 2047);
    int b = bh / 12;
    float mq = (float)mask[b * S + sidx];
    x0 *= mq; x1 *= mq; x2 *= mq; x3 *= mq;
    float ss = x0 * x0 + x1 * x1 + x2 * x2 + x3 * x3;
    #pragma unroll
    for (int m = 1; m <= 8; m <<= 1) ss += __shfl_xor(ss, m, 64);
    float sc = rsqrtf(ss + 1e-6f);
    float4 o = { x0 * sc, x1 * sc, x2 * sc, x3 * sc };
    *(float4*)(out + i) = o;
}

extern "C" void kernel_launch(void* const* d_in, const int* in_sizes, int n_in,
                              void* d_out, int out_size, void* d_ws, size_t ws_size,
                              hipStream_t stream) {
    const float* Q    = (const float*)d_in[0];
    const float* K    = (const float*)d_in[1];
    const float* V    = (const float*)d_in[2];
    const int*   mask = (const int*)d_in[3];
    const int*   hlen = (const int*)d_in[4];
    float*       out  = (float*)d_out;

    __hip_bfloat16* Qn = (__hip_bfloat16*)d_ws;
    __hip_bfloat16* Kn = Qn + (size_t)NBH * S * D;
    __half*         Vt = (__half*)(Kn + (size_t)NBH * S * D);
    __half* Pbuf = (__half*)((char*)d_ws + 3ull * NBH * S * D * 2);  // fp16 partials

    const size_t base_b = 3ull * NBH * S * D * 2;    // Qn + Kn + Vt (18.9 MB)
    const size_t part_h = (size_t)NBH * S * D * 2;   // one fp16 partial buffer

    prep<<<2 * NBH * S / 16 + NBH * 32, 256, 0, stream>>>(Q, K, V, mask, Qn, Kn, Vt);
    if (ws_size >= base_b + 4 * part_h) {            // 44.04 MB (proven budget)
        yoso_main<4><<<NBH * 8 * 4, 512, 0, stream>>>(Qn, Kn, Vt, mask, hlen, Pbuf);
        combine_norm<4><<<NBH * S / 16, 256, 0, stream>>>(Pbuf, mask, out);
    } else if (ws_size >= base_b + 2 * part_h) {
        yoso_main<2><<<NBH * 8 * 2, 512, 0, stream>>>(Qn, Kn, Vt, mask, hlen, Pbuf);
        combine_norm<2><<<NBH * S / 16, 256, 0, stream>>>(Pbuf, mask, out);
    } else {
        yoso_main<1><<<NBH * 8, 512, 0, stream>>>(Qn, Kn, Vt, mask, hlen, out);
    }
}